// Round 11
// baseline (147.045 us; speedup 1.0000x reference)
//
#include <hip/hip_runtime.h>
#include <hip/hip_bf16.h>

// ---------------------------------------------------------------------------
// Fused: LN -> qkv GEMM (+RoPE/bilinear/v-transpose epilogues) -> flash attn
//        -> out GEMM.  B=1, N=2048, DIM=1024, HEADS=16, DHEAD=64.
// R24 = R20 base + BARRIER-FREE attn K-loop:
//   K and V fragments are 16 contiguous bytes in global (kth [n][64],
//   vt [d][2048]) and K/V per head = 512KB = L2-resident (8 blocks share) ->
//   load fragments DIRECT from global, delete K/V LDS staging AND both
//   per-jt barriers.  Waves run fully independent; P stays in per-wave
//   LDS (proven same-wave path).  One barrier before merge (R13 form).
//   LDS 48KB -> 3 blocks/CU, launch_bounds(256,3).
// Theory: R14/R21/R22/R23 showed attn insensitive to dbuf/occupancy/trims --
// the cost is the lockstep vmcnt(0)+barrier pair every jt.  Remove the
// fences, not tune around them.
// Journal: R15/16 fusion 3.6x WORSE. R17 transpose-on-load REGRESSED.
// R18 qkv 64x128 WIN. R19 setprio REGRESSED. R20 gemm64 BK=128 WIN (140.2).
// R21 q-split REGRESSED. R22 trims NEUTRAL. R23 occupancy NEUTRAL.
// ~45us of dur_us is harness poison fill.
// ---------------------------------------------------------------------------

typedef unsigned short u16;
typedef __attribute__((ext_vector_type(4))) float f32x4;
typedef __attribute__((ext_vector_type(8))) __bf16 bf16x8;

struct alignas(8) US4 { u16 x, y, z, w; };

__device__ __forceinline__ u16 f2bf(float f) {
  union { float f; unsigned u; } v; v.f = f;
  unsigned r = v.u + 0x7FFFu + ((v.u >> 16) & 1u);   // RNE
  return (u16)(r >> 16);
}
// packed f32 pair -> bf16x2 (v_cvt_pk_bf16_f32, RNE -- bit-identical to f2bf)
__device__ __forceinline__ unsigned pk2bf(float a, float b) {
  float2 f; f.x = a; f.y = b;
  __hip_bfloat162 h = __float22bfloat162_rn(f);
  union { __hip_bfloat162 h; unsigned u; } v; v.h = h;
  return v.u;
}

typedef void GVOID __attribute__((address_space(1)));
typedef void LVOID __attribute__((address_space(3)));

#if defined(__has_builtin)
#if __has_builtin(__builtin_amdgcn_global_load_lds)
#define HAS_GLD_LDS 1
#endif
#endif

__device__ __forceinline__ void gld16(const void* g, void* l) {
#ifdef HAS_GLD_LDS
  __builtin_amdgcn_global_load_lds((GVOID*)(void*)g, (LVOID*)l, 16, 0, 0);
#else
  struct alignas(16) U4 { unsigned a, b, c, d; };
  *(U4*)l = *(const U4*)g;
#endif
}

__device__ __forceinline__ f32x4 MFMA(bf16x8 a, bf16x8 b, f32x4 c) {
  return __builtin_amdgcn_mfma_f32_16x16x32_bf16(a, b, c, 0, 0, 0);
}

// LDS swizzle for 64B-row tiles (32 u16/row, 4 x 16B chunks)
__device__ __forceinline__ int swz(int r, int q) {   // u16 index
  return r * 32 + ((q ^ ((r >> 1) & 3)) << 3);
}
__device__ __forceinline__ int swz_src_colb(int o) { // byte offset in 64B row
  const int r = o >> 6;
  return ((((o >> 4) & 3) ^ ((r >> 1) & 3)) << 4);
}
// merge-phase f32 [64][64] arrays: 16B chunk c of row ee at chunk c^(ee&15)
__device__ __forceinline__ int mswz4(int ee, int c) {  // f32 idx, 16B chunk
  return ee * 64 + ((c ^ (ee & 15)) << 2);
}
__device__ __forceinline__ int mswz1(int ee, int q) {  // f32 idx, scalar q
  return ee * 64 + ((((q >> 2) ^ (ee & 15)) << 2) | (q & 3));
}

// ---------------------------------------------------------------------------
// prep: weight transposes (+bf16 cast, 64x64 tiles) and LayerNorm.
// grid: [0,256) Wq | [256,768) Wkv | [768,1024) Wo | [1024,1040) Wb |
//       [1040,3088) LN rows.
// ---------------------------------------------------------------------------
__global__ __launch_bounds__(256) void prep_kernel(
    const float* __restrict__ x, const float* __restrict__ gamma,
    const float* __restrict__ Wq, const float* __restrict__ Wkv,
    const float* __restrict__ Wo, const float* __restrict__ Wb,
    u16* __restrict__ xn, u16* __restrict__ wqkvT, u16* __restrict__ woT,
    u16* __restrict__ wbT) {
  __shared__ __align__(16) float smem[64 * 65];   // 16.6KB
  const int bid = blockIdx.x, t = threadIdx.x;
  if (bid < 1040) {
    const float* src; u16* dst; int C, R, bx, by;
    if (bid < 256)      { src = Wq;  dst = wqkvT; R = 1024; C = 1024; bx = bid & 15; by = bid >> 4; }
    else if (bid < 768) { int i = bid - 256; src = Wkv; dst = wqkvT + 1024 * 1024; R = 1024; C = 2048; bx = i & 31; by = i >> 5; }
    else if (bid < 1024){ int i = bid - 768; src = Wo;  dst = woT; R = 1024; C = 1024; bx = i & 15; by = i >> 4; }
    else { int h = bid - 1024; src = Wb + (size_t)h * 4096; dst = wbT + (size_t)h * 4096; R = 64; C = 64; bx = 0; by = 0; }
    float (*tile)[65] = (float(*)[65])smem;
    const int c0 = bx * 64, r0 = by * 64;
    const int tx = t & 63, ty = t >> 6;  // 64 x 4
#pragma unroll
    for (int i = 0; i < 16; i++)
      tile[ty + i * 4][tx] = src[(size_t)(r0 + ty + i * 4) * C + c0 + tx];
    __syncthreads();
#pragma unroll
    for (int i = 0; i < 16; i++)
      dst[(size_t)(c0 + ty + i * 4) * R + r0 + tx] = f2bf(tile[tx][ty + i * 4]);
  } else {
    const int n = bid - 1040;
    const int w = t >> 6, lane = t & 63;
    const float4 v = *(const float4*)&x[(size_t)n * 1024 + t * 4];
    float s = v.x + v.y + v.z + v.w;
    float q = v.x * v.x + v.y * v.y + v.z * v.z + v.w * v.w;
#pragma unroll
    for (int off = 32; off; off >>= 1) {
      s += __shfl_down(s, off);
      q += __shfl_down(q, off);
    }
    if (lane == 0) { smem[w] = s; smem[4 + w] = q; }
    __syncthreads();
    s = smem[0] + smem[1] + smem[2] + smem[3];
    q = smem[4] + smem[5] + smem[6] + smem[7];
    const float mean = s * (1.0f / 1024.0f);
    const float var = q * (1.0f / 1024.0f) - mean * mean;
    const float inv = rsqrtf(var + 1e-5f);
    const float4 g = *(const float4*)&gamma[t * 4];
    US4 o;
    o.x = f2bf((v.x - mean) * inv * g.x);
    o.y = f2bf((v.y - mean) * inv * g.y);
    o.z = f2bf((v.z - mean) * inv * g.z);
    o.w = f2bf((v.w - mean) * inv * g.w);
    *(US4*)&xn[(size_t)n * 1024 + t * 4] = o;
  }
}

// ---------------------------------------------------------------------------
// qkv GEMM, 64x128 tile, BK=64, grid (24,32) = 768 blocks (R18-proven).
// LDS: As 8K + Bs 16K + krs 16K = 40KB -> 3-4 blocks/CU resident.
// Waves: 2m x 2n -> wave owns 32m x 64n, acc[2][4].
// Epilogues by region: q rope*0.125 -> qh | k rope -> krs -> @wbT -> kth |
//                      v cast -> vt.
// ---------------------------------------------------------------------------
__global__ __launch_bounds__(256, 2) void gemm_qkv(
    const u16* __restrict__ A, const u16* __restrict__ B,
    const u16* __restrict__ wbT, u16* __restrict__ qh,
    u16* __restrict__ kth, u16* __restrict__ vt) {
  __shared__ u16 As[2 * 64 * 32];    // 8KB  [ksub][row64][k32] swz
  __shared__ u16 Bs[2 * 128 * 32];   // 16KB [ksub][row128][k32] swz
  __shared__ u16 krs[2 * 4096];      // 16KB: [head2][dsub2][row64][d32] swz
  const int K = 1024;
  const int t = threadIdx.x;
  const int w = t >> 6, lane = t & 63, quad = lane >> 4, cc = lane & 15;
  const int bm = blockIdx.y << 6, bn = blockIdx.x << 7;
  const int wm = (w >> 1) << 5, wn = (w & 1) << 6;
  const f32x4 fzero = {0.f, 0.f, 0.f, 0.f};
  f32x4 acc[2][4];
#pragma unroll
  for (int i = 0; i < 2; i++)
#pragma unroll
    for (int j = 0; j < 4; j++) acc[i][j] = fzero;

  const char* gA = (const char*)A;
  const char* gB = (const char*)B;
  for (int k0 = 0; k0 < K; k0 += 64) {
    __syncthreads();
#pragma unroll
    for (int i = 0; i < 2; i++) {   // A: 64x64 = 8KB
      const int o = (i * 256 + t) * 16;
      const int sub = o >> 12, row = (o >> 6) & 63, colb = swz_src_colb(o);
      gld16(gA + (((size_t)(bm + row) * K + k0 + sub * 32) << 1) + colb, (char*)As + o);
    }
#pragma unroll
    for (int i = 0; i < 4; i++) {   // B: 128x64 = 16KB
      const int o = (i * 256 + t) * 16;
      const int sub = o >> 13, row = (o >> 6) & 127, colb = swz_src_colb(o);
      gld16(gB + (((size_t)(bn + row) * K + k0 + sub * 32) << 1) + colb, (char*)Bs + o);
    }
    __syncthreads();
#pragma unroll
    for (int ks = 0; ks < 2; ks++) {
      bf16x8 af[2], bfr[4];
#pragma unroll
      for (int mi = 0; mi < 2; mi++)
        af[mi] = *(const bf16x8*)&As[ks * 2048 + swz(wm + mi * 16 + cc, quad)];
#pragma unroll
      for (int ni = 0; ni < 4; ni++)
        bfr[ni] = *(const bf16x8*)&Bs[ks * 4096 + swz(wn + ni * 16 + cc, quad)];
#pragma unroll
      for (int mi = 0; mi < 2; mi++)
#pragma unroll
        for (int ni = 0; ni < 4; ni++)
          acc[mi][ni] = MFMA(af[mi], bfr[ni], acc[mi][ni]);
    }
  }

  const int region = blockIdx.x >> 3;  // 0=q, 1=k, 2=v (uniform per block)
  if (region == 0) {
    // ---- q: rope * 0.125 -> qh ----
#pragma unroll
    for (int ni = 0; ni < 4; ni++) {
      const int col = bn + wn + ni * 16 + cc;
      const int h = (col >> 6) & 15, d = col & 63;
      const float theta = __expf(-(float)(col & 31) * 0.2878231366242557f);
      const float sgn = (col & 1) ? 1.0f : -1.0f;
#pragma unroll
      for (int mi = 0; mi < 2; mi++) {
        const int row0 = bm + wm + mi * 16 + quad * 4;
#pragma unroll
        for (int r = 0; r < 4; r++) {
          const float val = acc[mi][ni][r];
          const float pr = __shfl_xor(val, 1);
          float sv, cv;
          __sincosf(theta * (float)(row0 + r), &sv, &cv);
          qh[((size_t)h * 2048 + row0 + r) * 64 + d] =
              f2bf((val * cv + sgn * pr * sv) * 0.125f);
        }
      }
    }
  } else if (region == 2) {
    // ---- v: direct transpose write vt[h][d][n] ----
#pragma unroll
    for (int ni = 0; ni < 4; ni++) {
      const int col = bn + wn + ni * 16 + cc;
      const int h = (col >> 6) & 15, d = col & 63;
      u16* base = vt + ((size_t)h * 64 + d) * 2048;
#pragma unroll
      for (int mi = 0; mi < 2; mi++) {
        const int row0 = bm + wm + mi * 16 + quad * 4;
        uint2 pk;
        pk.x = pk2bf(acc[mi][ni][0], acc[mi][ni][1]);
        pk.y = pk2bf(acc[mi][ni][2], acc[mi][ni][3]);
        *(uint2*)&base[row0] = pk;
      }
    }
  } else {
    // ---- k: rope -> krs (A-layout, swz, 64 rows/head) ----
    const int h2 = w & 1;
    u16* krh = krs + h2 * 4096;
#pragma unroll
    for (int ni = 0; ni < 4; ni++) {
      const int dloc = ni * 16 + cc;
      const int dsub = dloc >> 5;
      const int chunk = (dloc & 31) >> 3, elem = dloc & 7;
      const int col = bn + wn + ni * 16 + cc;
      const float theta = __expf(-(float)(col & 31) * 0.2878231366242557f);
      const float sgn = (col & 1) ? 1.0f : -1.0f;
#pragma unroll
      for (int mi = 0; mi < 2; mi++) {
        const int lrow0 = wm + mi * 16 + quad * 4;
#pragma unroll
        for (int r = 0; r < 4; r++) {
          const float val = acc[mi][ni][r];
          const float pr = __shfl_xor(val, 1);
          float sv, cv;
          __sincosf(theta * (float)(bm + lrow0 + r), &sv, &cv);
          const int row = lrow0 + r;
          krh[dsub * 2048 + row * 32 + ((chunk ^ ((row >> 1) & 3)) << 3) + elem] =
              f2bf(val * cv + sgn * pr * sv);
        }
      }
    }
    __syncthreads();
    // stage wbT for both heads into As (8KB) / Bs (first 8KB)
    const int hg0 = (bn >> 6) & 15;
#pragma unroll
    for (int i = 0; i < 2; i++) {
      const int o = (i * 256 + t) * 16;
      const int row = o >> 6;
      const int dsub = row >> 6, e = row & 63;
      const int colb = swz_src_colb(o);
      gld16((const char*)wbT + (((size_t)hg0 * 4096 + e * 64 + dsub * 32) << 1) + colb,
            (char*)As + o);
      gld16((const char*)wbT + (((size_t)(hg0 + 1) * 4096 + e * 64 + dsub * 32) << 1) + colb,
            (char*)Bs + o);
    }
    __syncthreads();
    const int wmrow = (w >> 1) << 5;
    const u16* Bsel = h2 ? Bs : As;
    f32x4 acc2[2][4];
#pragma unroll
    for (int i = 0; i < 2; i++)
#pragma unroll
      for (int j = 0; j < 4; j++) acc2[i][j] = fzero;
#pragma unroll
    for (int dsub = 0; dsub < 2; dsub++) {
      bf16x8 bfr[4];
#pragma unroll
      for (int et = 0; et < 4; et++)
        bfr[et] = *(const bf16x8*)&Bsel[swz(dsub * 64 + et * 16 + cc, quad)];
#pragma unroll
      for (int mi = 0; mi < 2; mi++) {
        const bf16x8 af = *(const bf16x8*)&krh[dsub * 2048 + swz(wmrow + mi * 16 + cc, quad)];
#pragma unroll
        for (int et = 0; et < 4; et++)
          acc2[mi][et] = MFMA(af, bfr[et], acc2[mi][et]);
      }
    }
    u16* Ck = kth + (size_t)(hg0 + h2) * 2048 * 64;
#pragma unroll
    for (int mi = 0; mi < 2; mi++) {
      const int n0 = bm + wmrow + mi * 16 + quad * 4;
#pragma unroll
      for (int et = 0; et < 4; et++) {
        const int e = et * 16 + cc;
#pragma unroll
        for (int r = 0; r < 4; r++)
          Ck[(size_t)(n0 + r) * 64 + e] = f2bf(acc2[mi][et][r]);
      }
    }
  }
}

// ---------------------------------------------------------------------------
// Flash attention R24: BARRIER-FREE K-loop.  K/V fragments loaded direct
// from global (L2-resident: 512KB/head shared by 8 blocks):
//   kf = kth[h][j][ds*32+quad*8] (16B contiguous),
//   vf = vt[h][e][j0+w*32+quad*8] (16B contiguous).
// No K/V LDS staging, no per-jt barriers -- waves fully independent.
// P transport stays in per-wave-private LDS (proven same-wave path).
// One barrier before merge (R13 3-barrier form).  LDS 48KB -> 3 blocks/CU.
// One block = one head x 64 q-rows; grid 512.  Wave w owns j-stripe
// [w*32,w*32+32).  No-max softmax; l via MFMA-with-ones.
// ---------------------------------------------------------------------------
__global__ __launch_bounds__(256, 3) void attn_kernel(
    const u16* __restrict__ qh, const u16* __restrict__ kth,
    const u16* __restrict__ vt, u16* __restrict__ aout) {
  __shared__ __align__(16) u16 lds[24576];   // 48KB
  u16* const Ks = lds;            // merge: O-half A f32[64][64] swz (16KB)
  u16* const Vs = lds + 8192;     // merge: O-half B (16KB)
  u16* const Ps = lds + 16384;    // 16KB P tiles; merge: l partials
  const int t = threadIdx.x;
  const int w = t >> 6, lane = t & 63, quad = lane >> 4, cc = lane & 15;
  const int bid = blockIdx.x;
  const int h = (bid & 7) + ((bid >> 8) << 3);   // XCD-aware head mapping
  const int q0 = ((bid >> 3) & 31) << 6;
  const size_t hq = (size_t)h * (2048 * 64);
  const f32x4 fzero = {0.f, 0.f, 0.f, 0.f};
  const int g4 = (cc >> 1) & 3;      // = (row>>1)&3 for row = X*16+cc

  bf16x8 ones;
  {
    union { u16 u; __bf16 b; } one; one.u = 0x3F80;  // bf16 1.0
#pragma unroll
    for (int i = 0; i < 8; i++) ones[i] = one.b;
  }

  // ---- Q direct to registers (16B contiguous per fragment) ----
  bf16x8 qf[4][2];
#pragma unroll
  for (int qn = 0; qn < 4; qn++)
#pragma unroll
    for (int ds = 0; ds < 2; ds++)
      qf[qn][ds] = *(const bf16x8*)&qh[hq + (size_t)(q0 + qn * 16 + cc) * 64 +
                                       ds * 32 + quad * 8];

  f32x4 oacc[4][4];
  f32x4 lacc[4];
#pragma unroll
  for (int mi = 0; mi < 4; mi++) {
    lacc[mi] = fzero;
#pragma unroll
    for (int et = 0; et < 4; et++) oacc[mi][et] = fzero;
  }

  u16* const psw = Ps + (w << 11);   // this wave's 4KB P tile (2048 u16)

  // per-lane loop-invariant global bases
  const u16* kbase = kth + hq + (size_t)(w * 32 + cc) * 64 + quad * 8;
  const u16* vbase = vt + hq + (size_t)cc * 2048 + w * 32 + quad * 8;

  for (int jt = 0; jt < 16; jt++) {
    const int j0 = jt << 7;

    // ---- S^T = K x Q^T; K fragments DIRECT from global (L2) ----
#pragma unroll
    for (int jm = 0; jm < 2; jm++) {
      const u16* krow = kbase + (size_t)(j0 + jm * 16) * 64;
      const bf16x8 kf0 = *(const bf16x8*)(krow);
      const bf16x8 kf1 = *(const bf16x8*)(krow + 32);
      const int c16 = ((jm << 1) + (quad >> 1)) ^ g4;    // phys 16B chunk
      const int coff = (c16 << 3) + ((quad & 1) << 2);   // u16 offset in row
#pragma unroll
      for (int qn = 0; qn < 4; qn++) {
        f32x4 s = MFMA(kf0, qf[qn][0], fzero);
        s = MFMA(kf1, qf[qn][1], s);
        uint2 pk;
        pk.x = pk2bf(__expf(s[0]), __expf(s[1]));
        pk.y = pk2bf(__expf(s[2]), __expf(s[3]));
        *(uint2*)&psw[((qn * 16 + cc) << 5) + coff] = pk;
      }
    }

    // ---- O += P*V, l += P*1; V fragments DIRECT from global (L2) ----
    bf16x8 vf[4];
#pragma unroll
    for (int et = 0; et < 4; et++)
      vf[et] = *(const bf16x8*)(vbase + (size_t)(et * 16) * 2048 + j0);
#pragma unroll
    for (int mi = 0; mi < 4; mi++) {
      const bf16x8 pa = *(const bf16x8*)&psw[swz(mi * 16 + cc, quad)];
      lacc[mi] = MFMA(pa, ones, lacc[mi]);
#pragma unroll
      for (int et = 0; et < 4; et++) oacc[mi][et] = MFMA(pa, vf[et], oacc[mi][et]);
    }
  }

  // ---- merge the 4 wave-partials (additive: no-max softmax; R13 form) ----
  float* OA = (float*)Ks;
  float* OB = (float*)Vs;
  float* lP = (float*)Ps;   // [0,64) lA | [64,128) lB | [128,192) l2 | [192,256) l3
  __syncthreads();          // waves desynced during barrier-free loop
  if (w >= 2) {
    float* dst = (w == 2) ? OA : OB;
#pragma unroll
    for (int mi = 0; mi < 4; mi++) {
#pragma unroll
      for (int et = 0; et < 4; et++) {
        const int ee = et * 16 + cc;
        *(f32x4*)&dst[mswz4(ee, mi * 4 + quad)] = oacc[mi][et];
      }
      if (cc == 0)
#pragma unroll
        for (int r = 0; r < 4; r++)
          lP[64 * w + mi * 16 + quad * 4 + r] = lacc[mi][r];
    }
  }
  __syncthreads();
  if (w < 2) {
    const float* src = (w == 0) ? OA : OB;
    const float* lsrc = &lP[64 * (w + 2)];
#pragma unroll
    for (int mi = 0; mi < 4; mi++) {
#pragma unroll
      for (int et = 0; et < 4; et++) {
        const int ee = et * 16 + cc;
        oacc[mi][et] += *(const f32x4*)&src[mswz4(ee, mi * 4 + quad)];
      }
#pragma unroll
      for (int r = 0; r < 4; r++)
        lacc[mi][r] += lsrc[mi * 16 + quad * 4 + r];
    }
  }
  __syncthreads();
  if (w < 2) {
    float* dst = (w == 0) ? OA : OB;
#pragma unroll
    for (int mi = 0; mi < 4; mi++) {
#pragma unroll
      for (int et = 0; et < 4; et++) {
        const int ee = et * 16 + cc;
        *(f32x4*)&dst[mswz4(ee, mi * 4 + quad)] = oacc[mi][et];
      }
      if (cc == 0)
#pragma unroll
        for (int r = 0; r < 4; r++)
          lP[64 * w + mi * 16 + quad * 4 + r] = lacc[mi][r];
    }
  }
  __syncthreads();
  {
    const int q = lane;
    const float linv = 1.0f / (lP[q] + lP[64 + q]);
    unsigned obuf[8];
#pragma unroll
    for (int e = 0; e < 8; e++) {
      const int e0 = w * 16 + e * 2, e1 = e0 + 1;
      obuf[e] = pk2bf((OA[mswz1(e0, q)] + OB[mswz1(e0, q)]) * linv,
                      (OA[mswz1(e1, q)] + OB[mswz1(e1, q)]) * linv);
    }
    uint4* dst = (uint4*)&aout[(size_t)(q0 + q) * 1024 + h * 64 + w * 16];
    dst[0] = *(uint4*)&obuf[0];
    dst[1] = *(uint4*)&obuf[4];
  }
}

// ---------------------------------------------------------------------------
// out = aout(2048x1024 bf16) @ woT -> f32.  64x64 tiles, BK=128 (8 k-iters,
// half the barrier drains), 512 blocks @ 32KB LDS -> 2 blocks/CU.
// ---------------------------------------------------------------------------
__global__ __launch_bounds__(256, 2) void gemm64_bt_f32(
    const u16* __restrict__ A, const u16* __restrict__ B, float* __restrict__ C,
    int M, int N, int K) {
  __shared__ u16 As[4 * 64 * 32];   // 16KB: [ksub0..3][row 64][k 32] swz
  __shared__ u16 Bs[4 * 64 * 32];   // 16KB
  const int t = threadIdx.x;
  const int w = t >> 6, lane = t & 63, quad = lane >> 4, cc = lane & 15;
  const int bm = blockIdx.y << 6, bn = blockIdx.x << 6;
  const int wm = (w >> 1) << 5, wn = (w & 1) << 5;
  const f32x4 fzero = {0.f, 0.f, 0.f, 0.f};
  f32x4 acc[2][2];
#pragma unroll
  for (int i = 0; i < 2; i++)
#pragma unroll
    for (int j = 0; j < 2; j++) acc[i][j] = fzero;

  const char* gA = (const char*)A;
  const char* gB = (const char*)B;
  for (int k0 = 0; k0 < K; k0 += 128) {
    __syncthreads();
#pragma unroll
    for (int i = 0; i < 4; i++) {   // A,B: 64 rows x 128 k = 16KB each
      const int o = (i * 256 + t) * 16;
      const int sub = o >> 12, row = (o >> 6) & 63, colb = swz_src_colb(o);
      gld16(gA + (((size_t)(bm + row) * K + k0 + sub * 32) << 1) + colb, (char*)As + o);
      gld16(gB + (((size_t)(bn + row) * K + k0 + sub * 32) << 1) + colb, (char*)Bs + o);
    }
    __syncthreads();
#pragma unroll
    for (int ks = 0; ks < 4; ks++) {
      bf16x8 af[2], bfr[2];
#pragma unroll
      for (int mi = 0; mi < 2; mi++)
        af[mi] = *(const bf16x8*)&As[ks * 2048 + swz(wm + mi * 16 + cc, quad)];
#pragma unroll
      for (int ni = 0; ni < 2; ni++)
        bfr[ni] = *(const bf16x8*)&Bs[ks * 2048 + swz(wn + ni * 16 + cc, quad)];
#pragma unroll
      for (int mi = 0; mi < 2; mi++)
#pragma unroll
        for (int ni = 0; ni < 2; ni++)
          acc[mi][ni] = MFMA(af[mi], bfr[ni], acc[mi][ni]);
    }
  }
#pragma unroll
  for (int mi = 0; mi < 2; mi++) {
    const int row = bm + wm + mi * 16 + quad * 4;
#pragma unroll
    for (int ni = 0; ni < 2; ni++) {
      const int col = bn + wn + ni * 16 + cc;
#pragma unroll
      for (int r = 0; r < 4; r++) C[(size_t)(row + r) * N + col] = acc[mi][ni][r];
    }
  }
}

// ---------------------------------------------------------------------------
// host side
// ---------------------------------------------------------------------------
extern "C" void kernel_launch(void* const* d_in, const int* in_sizes, int n_in,
                              void* d_out, int out_size, void* d_ws, size_t ws_size,
                              hipStream_t stream) {
  (void)in_sizes; (void)n_in; (void)out_size; (void)ws_size;
  const float* x     = (const float*)d_in[0];
  const float* gamma = (const float*)d_in[1];
  const float* Wq    = (const float*)d_in[2];
  const float* Wkv   = (const float*)d_in[3];
  const float* Wb    = (const float*)d_in[4];
  const float* Wo    = (const float*)d_in[5];
  float* out = (float*)d_out;
  char* ws = (char*)d_ws;

  const size_t OFF_XN    = 0;           // 4 MB
  const size_t OFF_WQKVT = 4194304;     // 6 MB
  const size_t OFF_WOT   = 10485760;    // 2 MB
  const size_t OFF_WBT   = 12582912;    // 128 KB
  const size_t OFF_QH    = 12713984;    // 4 MB
  const size_t OFF_KTH   = 16908288;    // 4 MB
  const size_t OFF_VT    = 21102592;    // 4 MB
  const size_t OFF_AOUT  = 25296896;    // 4 MB -> end ~29.5 MB

  u16* xn    = (u16*)(ws + OFF_XN);
  u16* wqkvT = (u16*)(ws + OFF_WQKVT);
  u16* woT   = (u16*)(ws + OFF_WOT);
  u16* wbT   = (u16*)(ws + OFF_WBT);
  u16* qh    = (u16*)(ws + OFF_QH);
  u16* kth   = (u16*)(ws + OFF_KTH);
  u16* vt    = (u16*)(ws + OFF_VT);
  u16* aout  = (u16*)(ws + OFF_AOUT);

  prep_kernel<<<3088, 256, 0, stream>>>(x, gamma, Wq, Wkv, Wo, Wb,
                                        xn, wqkvT, woT, wbT);
  gemm_qkv<<<dim3(24, 32), 256, 0, stream>>>(xn, wqkvT, wbT, qh, kth, vt);
  attn_kernel<<<512, 256, 0, stream>>>(qh, kth, vt, aout);
  gemm64_bt_f32<<<dim3(16, 32), 256, 0, stream>>>(aout, woT, out, 2048, 1024, 1024);
}

// Round 12
// 139.913 us; speedup vs baseline: 1.0510x; 1.0510x over previous
//
#include <hip/hip_runtime.h>
#include <hip/hip_bf16.h>

// ---------------------------------------------------------------------------
// Fused: LN -> qkv GEMM (+RoPE/bilinear/v-transpose epilogues) -> flash attn
//        -> out GEMM.  B=1, N=2048, DIM=1024, HEADS=16, DHEAD=64.
// R25 = FINAL: exact R20 configuration (session best, 140.2us).
//   prep: transposes + LN (3088 blocks).
//   gemm_qkv: 64x128 tile, BK=64, 768 blocks @ 40KB (R18 WIN).
//   attn: R14 dbuf prefetch-ahead, 80KB, 2/CU (best measured attn form).
//   gemm64: 64x64, BK=128, 512 blocks @ 32KB (R20 WIN).
// Experiment record (what moved / what didn't):
//   WINS: qkv 64x128 re-tile (R18, -4.8us); gemm64 BK=128 (R20, -2).
//   NEUTRAL: attn dbuf (R14), attn trims (R22), attn 3-blocks/CU (R23).
//   REGRESSIONS: coop-fusion grid.sync (R15/16, 3.6x), transpose-on-load
//     (R17, bank conflicts), setprio in lockstep waves (R19, m190),
//     attn q-split (R21, staging/compute ratio broken), attn barrier-free
//     direct-L2 (R24, lost LDS sharing + exposed L2 latency).
//   attn is invariant under every overlap/occupancy/sync/staging axis
//   tried; ~45us of dur_us is the harness poison fill (untouchable).
// ---------------------------------------------------------------------------

typedef unsigned short u16;
typedef __attribute__((ext_vector_type(4))) float f32x4;
typedef __attribute__((ext_vector_type(8))) __bf16 bf16x8;

struct alignas(8) US4 { u16 x, y, z, w; };

__device__ __forceinline__ u16 f2bf(float f) {
  union { float f; unsigned u; } v; v.f = f;
  unsigned r = v.u + 0x7FFFu + ((v.u >> 16) & 1u);   // RNE
  return (u16)(r >> 16);
}
// packed f32 pair -> bf16x2 (v_cvt_pk_bf16_f32, RNE -- bit-identical to f2bf)
__device__ __forceinline__ unsigned pk2bf(float a, float b) {
  float2 f; f.x = a; f.y = b;
  __hip_bfloat162 h = __float22bfloat162_rn(f);
  union { __hip_bfloat162 h; unsigned u; } v; v.h = h;
  return v.u;
}

typedef void GVOID __attribute__((address_space(1)));
typedef void LVOID __attribute__((address_space(3)));

#if defined(__has_builtin)
#if __has_builtin(__builtin_amdgcn_global_load_lds)
#define HAS_GLD_LDS 1
#endif
#endif

__device__ __forceinline__ void gld16(const void* g, void* l) {
#ifdef HAS_GLD_LDS
  __builtin_amdgcn_global_load_lds((GVOID*)(void*)g, (LVOID*)l, 16, 0, 0);
#else
  struct alignas(16) U4 { unsigned a, b, c, d; };
  *(U4*)l = *(const U4*)g;
#endif
}

__device__ __forceinline__ f32x4 MFMA(bf16x8 a, bf16x8 b, f32x4 c) {
  return __builtin_amdgcn_mfma_f32_16x16x32_bf16(a, b, c, 0, 0, 0);
}

// LDS swizzle for 64B-row tiles (32 u16/row, 4 x 16B chunks)
__device__ __forceinline__ int swz(int r, int q) {   // u16 index
  return r * 32 + ((q ^ ((r >> 1) & 3)) << 3);
}
__device__ __forceinline__ int swz_src_colb(int o) { // byte offset in 64B row
  const int r = o >> 6;
  return ((((o >> 4) & 3) ^ ((r >> 1) & 3)) << 4);
}
// merge-phase f32 [64][64] arrays: 16B chunk c of row ee at chunk c^(ee&15)
__device__ __forceinline__ int mswz4(int ee, int c) {  // f32 idx, 16B chunk
  return ee * 64 + ((c ^ (ee & 15)) << 2);
}
__device__ __forceinline__ int mswz1(int ee, int q) {  // f32 idx, scalar q
  return ee * 64 + ((((q >> 2) ^ (ee & 15)) << 2) | (q & 3));
}

// ---------------------------------------------------------------------------
// prep: weight transposes (+bf16 cast, 64x64 tiles) and LayerNorm.
// grid: [0,256) Wq | [256,768) Wkv | [768,1024) Wo | [1024,1040) Wb |
//       [1040,3088) LN rows.
// ---------------------------------------------------------------------------
__global__ __launch_bounds__(256) void prep_kernel(
    const float* __restrict__ x, const float* __restrict__ gamma,
    const float* __restrict__ Wq, const float* __restrict__ Wkv,
    const float* __restrict__ Wo, const float* __restrict__ Wb,
    u16* __restrict__ xn, u16* __restrict__ wqkvT, u16* __restrict__ woT,
    u16* __restrict__ wbT) {
  __shared__ __align__(16) float smem[64 * 65];   // 16.6KB
  const int bid = blockIdx.x, t = threadIdx.x;
  if (bid < 1040) {
    const float* src; u16* dst; int C, R, bx, by;
    if (bid < 256)      { src = Wq;  dst = wqkvT; R = 1024; C = 1024; bx = bid & 15; by = bid >> 4; }
    else if (bid < 768) { int i = bid - 256; src = Wkv; dst = wqkvT + 1024 * 1024; R = 1024; C = 2048; bx = i & 31; by = i >> 5; }
    else if (bid < 1024){ int i = bid - 768; src = Wo;  dst = woT; R = 1024; C = 1024; bx = i & 15; by = i >> 4; }
    else { int h = bid - 1024; src = Wb + (size_t)h * 4096; dst = wbT + (size_t)h * 4096; R = 64; C = 64; bx = 0; by = 0; }
    float (*tile)[65] = (float(*)[65])smem;
    const int c0 = bx * 64, r0 = by * 64;
    const int tx = t & 63, ty = t >> 6;  // 64 x 4
#pragma unroll
    for (int i = 0; i < 16; i++)
      tile[ty + i * 4][tx] = src[(size_t)(r0 + ty + i * 4) * C + c0 + tx];
    __syncthreads();
#pragma unroll
    for (int i = 0; i < 16; i++)
      dst[(size_t)(c0 + ty + i * 4) * R + r0 + tx] = f2bf(tile[tx][ty + i * 4]);
  } else {
    const int n = bid - 1040;
    const int w = t >> 6, lane = t & 63;
    const float4 v = *(const float4*)&x[(size_t)n * 1024 + t * 4];
    float s = v.x + v.y + v.z + v.w;
    float q = v.x * v.x + v.y * v.y + v.z * v.z + v.w * v.w;
#pragma unroll
    for (int off = 32; off; off >>= 1) {
      s += __shfl_down(s, off);
      q += __shfl_down(q, off);
    }
    if (lane == 0) { smem[w] = s; smem[4 + w] = q; }
    __syncthreads();
    s = smem[0] + smem[1] + smem[2] + smem[3];
    q = smem[4] + smem[5] + smem[6] + smem[7];
    const float mean = s * (1.0f / 1024.0f);
    const float var = q * (1.0f / 1024.0f) - mean * mean;
    const float inv = rsqrtf(var + 1e-5f);
    const float4 g = *(const float4*)&gamma[t * 4];
    US4 o;
    o.x = f2bf((v.x - mean) * inv * g.x);
    o.y = f2bf((v.y - mean) * inv * g.y);
    o.z = f2bf((v.z - mean) * inv * g.z);
    o.w = f2bf((v.w - mean) * inv * g.w);
    *(US4*)&xn[(size_t)n * 1024 + t * 4] = o;
  }
}

// ---------------------------------------------------------------------------
// qkv GEMM, 64x128 tile, BK=64, grid (24,32) = 768 blocks (R18-proven).
// LDS: As 8K + Bs 16K + krs 16K = 40KB -> 3-4 blocks/CU resident.
// Waves: 2m x 2n -> wave owns 32m x 64n, acc[2][4].
// Epilogues by region: q rope*0.125 -> qh | k rope -> krs -> @wbT -> kth |
//                      v cast -> vt.
// ---------------------------------------------------------------------------
__global__ __launch_bounds__(256, 2) void gemm_qkv(
    const u16* __restrict__ A, const u16* __restrict__ B,
    const u16* __restrict__ wbT, u16* __restrict__ qh,
    u16* __restrict__ kth, u16* __restrict__ vt) {
  __shared__ u16 As[2 * 64 * 32];    // 8KB  [ksub][row64][k32] swz
  __shared__ u16 Bs[2 * 128 * 32];   // 16KB [ksub][row128][k32] swz
  __shared__ u16 krs[2 * 4096];      // 16KB: [head2][dsub2][row64][d32] swz
  const int K = 1024;
  const int t = threadIdx.x;
  const int w = t >> 6, lane = t & 63, quad = lane >> 4, cc = lane & 15;
  const int bm = blockIdx.y << 6, bn = blockIdx.x << 7;
  const int wm = (w >> 1) << 5, wn = (w & 1) << 6;
  const f32x4 fzero = {0.f, 0.f, 0.f, 0.f};
  f32x4 acc[2][4];
#pragma unroll
  for (int i = 0; i < 2; i++)
#pragma unroll
    for (int j = 0; j < 4; j++) acc[i][j] = fzero;

  const char* gA = (const char*)A;
  const char* gB = (const char*)B;
  for (int k0 = 0; k0 < K; k0 += 64) {
    __syncthreads();
#pragma unroll
    for (int i = 0; i < 2; i++) {   // A: 64x64 = 8KB
      const int o = (i * 256 + t) * 16;
      const int sub = o >> 12, row = (o >> 6) & 63, colb = swz_src_colb(o);
      gld16(gA + (((size_t)(bm + row) * K + k0 + sub * 32) << 1) + colb, (char*)As + o);
    }
#pragma unroll
    for (int i = 0; i < 4; i++) {   // B: 128x64 = 16KB
      const int o = (i * 256 + t) * 16;
      const int sub = o >> 13, row = (o >> 6) & 127, colb = swz_src_colb(o);
      gld16(gB + (((size_t)(bn + row) * K + k0 + sub * 32) << 1) + colb, (char*)Bs + o);
    }
    __syncthreads();
#pragma unroll
    for (int ks = 0; ks < 2; ks++) {
      bf16x8 af[2], bfr[4];
#pragma unroll
      for (int mi = 0; mi < 2; mi++)
        af[mi] = *(const bf16x8*)&As[ks * 2048 + swz(wm + mi * 16 + cc, quad)];
#pragma unroll
      for (int ni = 0; ni < 4; ni++)
        bfr[ni] = *(const bf16x8*)&Bs[ks * 4096 + swz(wn + ni * 16 + cc, quad)];
#pragma unroll
      for (int mi = 0; mi < 2; mi++)
#pragma unroll
        for (int ni = 0; ni < 4; ni++)
          acc[mi][ni] = MFMA(af[mi], bfr[ni], acc[mi][ni]);
    }
  }

  const int region = blockIdx.x >> 3;  // 0=q, 1=k, 2=v (uniform per block)
  if (region == 0) {
    // ---- q: rope * 0.125 -> qh ----
#pragma unroll
    for (int ni = 0; ni < 4; ni++) {
      const int col = bn + wn + ni * 16 + cc;
      const int h = (col >> 6) & 15, d = col & 63;
      const float theta = __expf(-(float)(col & 31) * 0.2878231366242557f);
      const float sgn = (col & 1) ? 1.0f : -1.0f;
#pragma unroll
      for (int mi = 0; mi < 2; mi++) {
        const int row0 = bm + wm + mi * 16 + quad * 4;
#pragma unroll
        for (int r = 0; r < 4; r++) {
          const float val = acc[mi][ni][r];
          const float pr = __shfl_xor(val, 1);
          float sv, cv;
          __sincosf(theta * (float)(row0 + r), &sv, &cv);
          qh[((size_t)h * 2048 + row0 + r) * 64 + d] =
              f2bf((val * cv + sgn * pr * sv) * 0.125f);
        }
      }
    }
  } else if (region == 2) {
    // ---- v: direct transpose write vt[h][d][n] ----
#pragma unroll
    for (int ni = 0; ni < 4; ni++) {
      const int col = bn + wn + ni * 16 + cc;
      const int h = (col >> 6) & 15, d = col & 63;
      u16* base = vt + ((size_t)h * 64 + d) * 2048;
#pragma unroll
      for (int mi = 0; mi < 2; mi++) {
        const int row0 = bm + wm + mi * 16 + quad * 4;
        uint2 pk;
        pk.x = pk2bf(acc[mi][ni][0], acc[mi][ni][1]);
        pk.y = pk2bf(acc[mi][ni][2], acc[mi][ni][3]);
        *(uint2*)&base[row0] = pk;
      }
    }
  } else {
    // ---- k: rope -> krs (A-layout, swz, 64 rows/head) ----
    const int h2 = w & 1;
    u16* krh = krs + h2 * 4096;
#pragma unroll
    for (int ni = 0; ni < 4; ni++) {
      const int dloc = ni * 16 + cc;
      const int dsub = dloc >> 5;
      const int chunk = (dloc & 31) >> 3, elem = dloc & 7;
      const int col = bn + wn + ni * 16 + cc;
      const float theta = __expf(-(float)(col & 31) * 0.2878231366242557f);
      const float sgn = (col & 1) ? 1.0f : -1.0f;
#pragma unroll
      for (int mi = 0; mi < 2; mi++) {
        const int lrow0 = wm + mi * 16 + quad * 4;
#pragma unroll
        for (int r = 0; r < 4; r++) {
          const float val = acc[mi][ni][r];
          const float pr = __shfl_xor(val, 1);
          float sv, cv;
          __sincosf(theta * (float)(bm + lrow0 + r), &sv, &cv);
          const int row = lrow0 + r;
          krh[dsub * 2048 + row * 32 + ((chunk ^ ((row >> 1) & 3)) << 3) + elem] =
              f2bf(val * cv + sgn * pr * sv);
        }
      }
    }
    __syncthreads();
    // stage wbT for both heads into As (8KB) / Bs (first 8KB)
    const int hg0 = (bn >> 6) & 15;
#pragma unroll
    for (int i = 0; i < 2; i++) {
      const int o = (i * 256 + t) * 16;
      const int row = o >> 6;
      const int dsub = row >> 6, e = row & 63;
      const int colb = swz_src_colb(o);
      gld16((const char*)wbT + (((size_t)hg0 * 4096 + e * 64 + dsub * 32) << 1) + colb,
            (char*)As + o);
      gld16((const char*)wbT + (((size_t)(hg0 + 1) * 4096 + e * 64 + dsub * 32) << 1) + colb,
            (char*)Bs + o);
    }
    __syncthreads();
    const int wmrow = (w >> 1) << 5;
    const u16* Bsel = h2 ? Bs : As;
    f32x4 acc2[2][4];
#pragma unroll
    for (int i = 0; i < 2; i++)
#pragma unroll
      for (int j = 0; j < 4; j++) acc2[i][j] = fzero;
#pragma unroll
    for (int dsub = 0; dsub < 2; dsub++) {
      bf16x8 bfr[4];
#pragma unroll
      for (int et = 0; et < 4; et++)
        bfr[et] = *(const bf16x8*)&Bsel[swz(dsub * 64 + et * 16 + cc, quad)];
#pragma unroll
      for (int mi = 0; mi < 2; mi++) {
        const bf16x8 af = *(const bf16x8*)&krh[dsub * 2048 + swz(wmrow + mi * 16 + cc, quad)];
#pragma unroll
        for (int et = 0; et < 4; et++)
          acc2[mi][et] = MFMA(af, bfr[et], acc2[mi][et]);
      }
    }
    u16* Ck = kth + (size_t)(hg0 + h2) * 2048 * 64;
#pragma unroll
    for (int mi = 0; mi < 2; mi++) {
      const int n0 = bm + wmrow + mi * 16 + quad * 4;
#pragma unroll
      for (int et = 0; et < 4; et++) {
        const int e = et * 16 + cc;
#pragma unroll
        for (int r = 0; r < 4; r++)
          Ck[(size_t)(n0 + r) * 64 + e] = f2bf(acc2[mi][et][r]);
      }
    }
  }
}

// ---------------------------------------------------------------------------
// Flash attention (R14/R20 form: K/V double-buffered, prefetch-ahead; NO
// setprio).  One block = one head x 64 q-rows; grid 512.  Wave w owns
// j-stripe [w*32,w*32+32), all 64 q-rows.  No-max softmax; l via
// MFMA-with-ones; S^T so P writes are packed uint2 (16B-chunk swz); P read =
// plain b128.  Merge O-exchange uses mswz.  LDS 80KB, 2 blocks/CU.
// ---------------------------------------------------------------------------
__global__ __launch_bounds__(256, 2) void attn_kernel(
    const u16* __restrict__ qh, const u16* __restrict__ kth,
    const u16* __restrict__ vt, u16* __restrict__ aout) {
  __shared__ __align__(16) u16 lds[40960];   // 80KB
  u16* const Kb0 = lds;                      // 16KB; merge: OA f32[64][64] swz
  u16* const Kb1 = lds + 8192;               // 16KB; merge: OB
  u16* const Vb0 = lds + 16384;              // 16KB; merge: l partials
  u16* const Vb1 = lds + 24576;              // 16KB
  u16* const Ps  = lds + 32768;              // 16KB; prologue: Q staging (8KB)
  const int t = threadIdx.x;
  const int w = t >> 6, lane = t & 63, quad = lane >> 4, cc = lane & 15;
  const int bid = blockIdx.x;
  const int h = (bid & 7) + ((bid >> 8) << 3);   // XCD-aware head mapping
  const int q0 = ((bid >> 3) & 31) << 6;
  const size_t hq = (size_t)h * (2048 * 64);
  const f32x4 fzero = {0.f, 0.f, 0.f, 0.f};
  const int g4 = (cc >> 1) & 3;      // = (row>>1)&3 for row = X*16+cc

  bf16x8 ones;
  {
    union { u16 u; __bf16 b; } one; one.u = 0x3F80;  // bf16 1.0
#pragma unroll
    for (int i = 0; i < 8; i++) ones[i] = one.b;
  }

  bf16x8 qf[4][2];
  f32x4 oacc[4][4];
  f32x4 lacc[4];
#pragma unroll
  for (int mi = 0; mi < 4; mi++) {
    lacc[mi] = fzero;
#pragma unroll
    for (int et = 0; et < 4; et++) oacc[mi][et] = fzero;
  }

  u16* const psw = Ps + (w << 11);   // this wave's 4KB P tile (2048 u16)

  auto PREFETCH = [&](int jtn, u16* KD, u16* VD) {
    const int j0n = jtn << 7;
#pragma unroll
    for (int i = 0; i < 4; i++) {
      const int o = (i * 256 + t) * 16;
      const int colb = swz_src_colb(o);
      const int sub = o >> 13, row = (o >> 6) & 127;
      gld16((const char*)kth + ((hq + (size_t)(j0n + row) * 64 + sub * 32) << 1) + colb,
            (char*)KD + o);
      const int vsub = o >> 12, vrow = (o >> 6) & 63;
      gld16((const char*)vt + ((hq + (size_t)vrow * 2048 + j0n + vsub * 32) << 1) + colb,
            (char*)VD + o);
    }
  };

  auto COMPUTE = [&](const u16* KS, const u16* VS) {
#pragma unroll
    for (int jm = 0; jm < 2; jm++) {
      const bf16x8 kf0 = *(const bf16x8*)&KS[swz(w * 32 + jm * 16 + cc, quad)];
      const bf16x8 kf1 = *(const bf16x8*)&KS[swz(128 + w * 32 + jm * 16 + cc, quad)];
      const int c16 = ((jm << 1) + (quad >> 1)) ^ g4;    // phys 16B chunk
      const int coff = (c16 << 3) + ((quad & 1) << 2);   // u16 offset in row
#pragma unroll
      for (int qn = 0; qn < 4; qn++) {
        f32x4 s = MFMA(kf0, qf[qn][0], fzero);
        s = MFMA(kf1, qf[qn][1], s);
        uint2 pk;
        pk.x = pk2bf(__expf(s[0]), __expf(s[1]));
        pk.y = pk2bf(__expf(s[2]), __expf(s[3]));
        *(uint2*)&psw[((qn * 16 + cc) << 5) + coff] = pk;
      }
    }
    bf16x8 vf[4];
#pragma unroll
    for (int et = 0; et < 4; et++)
      vf[et] = *(const bf16x8*)&VS[swz(w * 64 + et * 16 + cc, quad)];
#pragma unroll
    for (int mi = 0; mi < 4; mi++) {
      const bf16x8 pa = *(const bf16x8*)&psw[swz(mi * 16 + cc, quad)];
      lacc[mi] = MFMA(pa, ones, lacc[mi]);
#pragma unroll
      for (int et = 0; et < 4; et++) oacc[mi][et] = MFMA(pa, vf[et], oacc[mi][et]);
    }
  };

  // ---- prologue: stage Q (64x64) into Ps; issue jt=0 into buf0 ----
#pragma unroll
  for (int i = 0; i < 2; i++) {
    const int o = (i * 256 + t) * 16;
    const int sub = o >> 12, row = (o >> 6) & 63, colb = swz_src_colb(o);
    gld16((const char*)qh + ((hq + (size_t)(q0 + row) * 64 + sub * 32) << 1) + colb,
          (char*)Ps + o);
  }
  PREFETCH(0, Kb0, Vb0);
  __syncthreads();
#pragma unroll
  for (int qn = 0; qn < 4; qn++)
#pragma unroll
    for (int ds = 0; ds < 2; ds++)
      qf[qn][ds] = *(const bf16x8*)&Ps[swz(ds * 64 + qn * 16 + cc, quad)];
  __syncthreads();   // all qf reads done before any wave's P-write into Ps

  for (int jt = 0; jt < 16; jt += 2) {
    PREFETCH(jt + 1, Kb1, Vb1);
    COMPUTE(Kb0, Vb0);
    __syncthreads();
    if (jt + 2 < 16) PREFETCH(jt + 2, Kb0, Vb0);
    COMPUTE(Kb1, Vb1);
    __syncthreads();
  }

  // ---- merge the 4 wave-partials (additive: no-max softmax) ----
  float* OA = (float*)Kb0;
  float* OB = (float*)Kb1;
  float* lP = (float*)Vb0;  // [0,64) lA | [64,128) lB | [128,192) l2 | [192,256) l3
  if (w >= 2) {
    float* dst = (w == 2) ? OA : OB;
#pragma unroll
    for (int mi = 0; mi < 4; mi++) {
#pragma unroll
      for (int et = 0; et < 4; et++) {
        const int ee = et * 16 + cc;
        *(f32x4*)&dst[mswz4(ee, mi * 4 + quad)] = oacc[mi][et];
      }
      if (cc == 0)
#pragma unroll
        for (int r = 0; r < 4; r++)
          lP[64 * w + mi * 16 + quad * 4 + r] = lacc[mi][r];
    }
  }
  __syncthreads();
  if (w < 2) {
    const float* src = (w == 0) ? OA : OB;
    const float* lsrc = &lP[64 * (w + 2)];
#pragma unroll
    for (int mi = 0; mi < 4; mi++) {
#pragma unroll
      for (int et = 0; et < 4; et++) {
        const int ee = et * 16 + cc;
        oacc[mi][et] += *(const f32x4*)&src[mswz4(ee, mi * 4 + quad)];
      }
#pragma unroll
      for (int r = 0; r < 4; r++)
        lacc[mi][r] += lsrc[mi * 16 + quad * 4 + r];
    }
  }
  __syncthreads();
  if (w < 2) {
    float* dst = (w == 0) ? OA : OB;
#pragma unroll
    for (int mi = 0; mi < 4; mi++) {
#pragma unroll
      for (int et = 0; et < 4; et++) {
        const int ee = et * 16 + cc;
        *(f32x4*)&dst[mswz4(ee, mi * 4 + quad)] = oacc[mi][et];
      }
      if (cc == 0)
#pragma unroll
        for (int r = 0; r < 4; r++)
          lP[64 * w + mi * 16 + quad * 4 + r] = lacc[mi][r];
    }
  }
  __syncthreads();
  {
    const int q = lane;
    const float linv = 1.0f / (lP[q] + lP[64 + q]);
    unsigned obuf[8];
#pragma unroll
    for (int e = 0; e < 8; e++) {
      const int e0 = w * 16 + e * 2, e1 = e0 + 1;
      obuf[e] = pk2bf((OA[mswz1(e0, q)] + OB[mswz1(e0, q)]) * linv,
                      (OA[mswz1(e1, q)] + OB[mswz1(e1, q)]) * linv);
    }
    uint4* dst = (uint4*)&aout[(size_t)(q0 + q) * 1024 + h * 64 + w * 16];
    dst[0] = *(uint4*)&obuf[0];
    dst[1] = *(uint4*)&obuf[4];
  }
}

// ---------------------------------------------------------------------------
// out = aout(2048x1024 bf16) @ woT -> f32.  64x64 tiles, BK=128 (8 k-iters,
// half the barrier drains), 512 blocks @ 32KB LDS -> 2 blocks/CU.
// ---------------------------------------------------------------------------
__global__ __launch_bounds__(256, 2) void gemm64_bt_f32(
    const u16* __restrict__ A, const u16* __restrict__ B, float* __restrict__ C,
    int M, int N, int K) {
  __shared__ u16 As[4 * 64 * 32];   // 16KB: [ksub0..3][row 64][k 32] swz
  __shared__ u16 Bs[4 * 64 * 32];   // 16KB
  const int t = threadIdx.x;
  const int w = t >> 6, lane = t & 63, quad = lane >> 4, cc = lane & 15;
  const int bm = blockIdx.y << 6, bn = blockIdx.x << 6;
  const int wm = (w >> 1) << 5, wn = (w & 1) << 5;
  const f32x4 fzero = {0.f, 0.f, 0.f, 0.f};
  f32x4 acc[2][2];
#pragma unroll
  for (int i = 0; i < 2; i++)
#pragma unroll
    for (int j = 0; j < 2; j++) acc[i][j] = fzero;

  const char* gA = (const char*)A;
  const char* gB = (const char*)B;
  for (int k0 = 0; k0 < K; k0 += 128) {
    __syncthreads();
#pragma unroll
    for (int i = 0; i < 4; i++) {   // A,B: 64 rows x 128 k = 16KB each
      const int o = (i * 256 + t) * 16;
      const int sub = o >> 12, row = (o >> 6) & 63, colb = swz_src_colb(o);
      gld16(gA + (((size_t)(bm + row) * K + k0 + sub * 32) << 1) + colb, (char*)As + o);
      gld16(gB + (((size_t)(bn + row) * K + k0 + sub * 32) << 1) + colb, (char*)Bs + o);
    }
    __syncthreads();
#pragma unroll
    for (int ks = 0; ks < 4; ks++) {
      bf16x8 af[2], bfr[2];
#pragma unroll
      for (int mi = 0; mi < 2; mi++)
        af[mi] = *(const bf16x8*)&As[ks * 2048 + swz(wm + mi * 16 + cc, quad)];
#pragma unroll
      for (int ni = 0; ni < 2; ni++)
        bfr[ni] = *(const bf16x8*)&Bs[ks * 2048 + swz(wn + ni * 16 + cc, quad)];
#pragma unroll
      for (int mi = 0; mi < 2; mi++)
#pragma unroll
        for (int ni = 0; ni < 2; ni++)
          acc[mi][ni] = MFMA(af[mi], bfr[ni], acc[mi][ni]);
    }
  }
#pragma unroll
  for (int mi = 0; mi < 2; mi++) {
    const int row = bm + wm + mi * 16 + quad * 4;
#pragma unroll
    for (int ni = 0; ni < 2; ni++) {
      const int col = bn + wn + ni * 16 + cc;
#pragma unroll
      for (int r = 0; r < 4; r++) C[(size_t)(row + r) * N + col] = acc[mi][ni][r];
    }
  }
}

// ---------------------------------------------------------------------------
// host side
// ---------------------------------------------------------------------------
extern "C" void kernel_launch(void* const* d_in, const int* in_sizes, int n_in,
                              void* d_out, int out_size, void* d_ws, size_t ws_size,
                              hipStream_t stream) {
  (void)in_sizes; (void)n_in; (void)out_size; (void)ws_size;
  const float* x     = (const float*)d_in[0];
  const float* gamma = (const float*)d_in[1];
  const float* Wq    = (const float*)d_in[2];
  const float* Wkv   = (const float*)d_in[3];
  const float* Wb    = (const float*)d_in[4];
  const float* Wo    = (const float*)d_in[5];
  float* out = (float*)d_out;
  char* ws = (char*)d_ws;

  const size_t OFF_XN    = 0;           // 4 MB
  const size_t OFF_WQKVT = 4194304;     // 6 MB
  const size_t OFF_WOT   = 10485760;    // 2 MB
  const size_t OFF_WBT   = 12582912;    // 128 KB
  const size_t OFF_QH    = 12713984;    // 4 MB
  const size_t OFF_KTH   = 16908288;    // 4 MB
  const size_t OFF_VT    = 21102592;    // 4 MB
  const size_t OFF_AOUT  = 25296896;    // 4 MB -> end ~29.5 MB

  u16* xn    = (u16*)(ws + OFF_XN);
  u16* wqkvT = (u16*)(ws + OFF_WQKVT);
  u16* woT   = (u16*)(ws + OFF_WOT);
  u16* wbT   = (u16*)(ws + OFF_WBT);
  u16* qh    = (u16*)(ws + OFF_QH);
  u16* kth   = (u16*)(ws + OFF_KTH);
  u16* vt    = (u16*)(ws + OFF_VT);
  u16* aout  = (u16*)(ws + OFF_AOUT);

  prep_kernel<<<3088, 256, 0, stream>>>(x, gamma, Wq, Wkv, Wo, Wb,
                                        xn, wqkvT, woT, wbT);
  gemm_qkv<<<dim3(24, 32), 256, 0, stream>>>(xn, wqkvT, wbT, qh, kth, vt);
  attn_kernel<<<512, 256, 0, stream>>>(qh, kth, vt, aout);
  gemm64_bt_f32<<<dim3(16, 32), 256, 0, stream>>>(aout, woT, out, 2048, 1024, 1024);
}